// Round 7
// baseline (721.686 us; speedup 1.0000x reference)
//
#include <hip/hip_runtime.h>
#include <hip/hip_bf16.h>
#include <cfloat>

#define NROWS 4096
#define DDIM 1024
#define NT 64                    // 64x64 tiles per dimension
#define NBLK (NT * (NT + 1) / 2) // 2080 triangular blocks
#define NSLOT (NT + 1)           // 65 partial slots per column

// acc = max(acc, |x|, |y|) -> v_max3_f32 with abs source modifiers.
#define MAX3ABS(ACC, X, Y) (ACC) = fmaxf(fmaxf(fabsf(X), fabsf(Y)), (ACC))

// lexicographic (val, idx) merge: keep smaller val, tie -> smaller idx
#define MERGE(BV, BI, V, I) \
    do { if ((V) < (BV) || ((V) == (BV) && (I) < (BI))) { BV = (V); BI = (I); } } while (0)

// global -> LDS direct copy, 16B per lane; LDS dest is wave-uniform base,
// HW writes base + lane*16 (m104). Swizzle lives in the per-lane SOURCE addr.
#define GLL16(GP, LP) \
    __builtin_amdgcn_global_load_lds((const __attribute__((address_space(1))) void*)(GP), \
                                     (__attribute__((address_space(3))) void*)(LP), 16, 0, 0)

// ---------------------------------------------------------------------------
// Kernel 1a: per-row max + normalize into ws (fast path). One wave per row.
// ---------------------------------------------------------------------------
__global__ __launch_bounds__(256) void normalize_kernel(const float* __restrict__ feats,
                                                        const int* __restrict__ normflag,
                                                        float* __restrict__ normf) {
    const int wave = threadIdx.x >> 6;
    const int lane = threadIdx.x & 63;
    const int row  = blockIdx.x * 4 + wave;
    const float* fr = feats + (size_t)row * DDIM;
    float*       fw = normf + (size_t)row * DDIM;
    float4 v[4];
    float m = 0.0f;  // feats uniform [0,1): nonnegative
#pragma unroll
    for (int k = 0; k < 4; ++k) {
        v[k] = *(const float4*)(fr + lane * 4 + k * 256);
        m = fmaxf(fmaxf(fmaxf(m, v[k].x), fmaxf(v[k].y, v[k].z)), v[k].w);
    }
#pragma unroll
    for (int off = 32; off > 0; off >>= 1) m = fmaxf(m, __shfl_xor(m, off));
    const float r = (*normflag != 0) ? m : 1.0f;
#pragma unroll
    for (int k = 0; k < 4; ++k) {
        v[k].x /= r; v[k].y /= r; v[k].z /= r; v[k].w /= r;
        *(float4*)(fw + lane * 4 + k * 256) = v[k];
    }
}

// Kernel 1b (fallback when ws is small): per-row max only.
__global__ __launch_bounds__(256) void rowmax_kernel(const float* __restrict__ feats,
                                                     const int* __restrict__ normflag,
                                                     float* __restrict__ rowmax) {
    const int wave = threadIdx.x >> 6;
    const int lane = threadIdx.x & 63;
    const int row  = blockIdx.x * 4 + wave;
    const float* fr = feats + (size_t)row * DDIM;
    float m = 0.0f;
    for (int d = lane * 4; d < DDIM; d += 256) {
        float4 v = *(const float4*)(fr + d);
        m = fmaxf(fmaxf(fmaxf(m, v.x), fmaxf(v.y, v.z)), v.w);
    }
#pragma unroll
    for (int off = 32; off > 0; off >>= 1) m = fmaxf(m, __shfl_xor(m, off));
    if (lane == 0) rowmax[row] = (*normflag != 0) ? m : 1.0f;
}

// ---------------------------------------------------------------------------
// Kernel 2: 256 threads (4 waves) per triangular 64x64 tile block; all 4
// waves hold full 8x8-per-lane accumulators over the same tile, split by q.
// Fast path (!NORM): double-buffered LDS (2 x 16 KB), global_load_lds width-16
// staging with pre-swizzled global source addresses (linear LDS dest), ONE
// barrier per 32-float d-chunk. launch_bounds(256,3) -> 3 blocks/CU so the
// CU-shared LDS pipe overlaps one block's ds_reads with another's VALU
// (round-6 lesson: at 2 lockstep blocks/CU the two pipes serialized,
// 331 us = 166 VALU + 187 LDS).
// Swizzle q^(row&7): A-reads 8 distinct rows per 16-lane group -> conflict-
// free; B-reads broadcast.
// ---------------------------------------------------------------------------
template <bool NORM>
__global__ __launch_bounds__(256, 3) void cheb_kernel(const float* __restrict__ src,
                                                      const float* __restrict__ rowmax,
                                                      const int* __restrict__ labels,
                                                      float* __restrict__ pval,
                                                      int* __restrict__ pidx) {
    // XCD-bijective swizzle (NBLK % 8 == 0), then triangular decode.
    int bid = blockIdx.x;
    bid = (bid & 7) * (NBLK / 8) + (bid >> 3);
    float fs = sqrtf((float)((2 * NT + 1) * (2 * NT + 1) - 8 * bid));
    int ta = (int)(((float)(2 * NT + 1) - fs) * 0.5f);
    while ((ta + 1) * NT - ((ta + 1) * ta) / 2 <= bid) ++ta;      // start(ta+1) <= bid
    while (ta * NT - (ta * (ta - 1)) / 2 > bid) --ta;             // start(ta)  >  bid
    const int tb = ta + (bid - (ta * NT - (ta * (ta - 1)) / 2));
    const int iBase = ta * 64;
    const int jBase = tb * 64;

    const int t    = threadIdx.x;
    const int w    = t >> 6;          // wave 0..3 (q-slice owner)
    const int lane = t & 63;
    const int ty8  = lane & 7;        // row group
    const int tx8  = lane >> 3;       // col group

    // 32 KB: [As0 8K | Bs0 8K | As1 8K | Bs1 8K]; merge reuses the first 16K.
    __shared__ __align__(16) float lds[8192];

    float acc[8][8];
#pragma unroll
    for (int kk = 0; kk < 8; ++kk)
#pragma unroll
        for (int jj = 0; jj < 8; ++jj) acc[kk][jj] = 0.0f;

    // Read bases (byte pointers), per buffer parity.
    const char* Ab0 = (const char*)(lds)        + ty8 * 128;
    const char* Bb0 = (const char*)(lds + 2048) + tx8 * 128;
    const char* Ab1 = (const char*)(lds + 4096) + ty8 * 128;
    const char* Bb1 = (const char*)(lds + 6144) + tx8 * 128;

#define COMPUTE(AB, BB) do {                                                  \
    _Pragma("unroll")                                                         \
    for (int qi = 0; qi < 2; ++qi) {                                          \
        const int q  = 2 * w + qi;                                            \
        const int oa = 16 * (q ^ ty8);                                        \
        const int ob = 16 * (q ^ tx8);                                        \
        float4 b[8];                                                          \
        _Pragma("unroll")                                                     \
        for (int jj = 0; jj < 8; ++jj)                                        \
            b[jj] = *(const float4*)((BB) + jj * 1024 + ob);                  \
        _Pragma("unroll")                                                     \
        for (int kk = 0; kk < 8; ++kk) {                                      \
            const float4 a = *(const float4*)((AB) + kk * 1024 + oa);         \
            _Pragma("unroll")                                                 \
            for (int jj = 0; jj < 8; ++jj) {                                  \
                const float d0 = a.x - b[jj].x;                               \
                const float d1 = a.y - b[jj].y;                               \
                const float d2 = a.z - b[jj].z;                               \
                const float d3 = a.w - b[jj].w;                               \
                MAX3ABS(acc[kk][jj], d0, d1);                                 \
                MAX3ABS(acc[kk][jj], d2, d3);                                 \
            }                                                                 \
        }                                                                     \
    } } while (0)

    if (!NORM) {
        // -------- fast path: global_load_lds double-buffer, 1 barrier/chunk.
        // Staging slots (float4 granularity, 512 per 8 KB tile): wave w covers
        // s = w*128 + n*64 + lane, n in {0,1}. slot s -> row = s>>3, c = s&7,
        // holding global chunk q = c ^ (row&7)  (swizzle in the SOURCE addr).
        const char* gAst[2];
        const char* gBst[2];
        char* ldsA0 = (char*)(lds)        + w * 2048;
        char* ldsB0 = (char*)(lds + 2048) + w * 2048;
        char* ldsA1 = (char*)(lds + 4096) + w * 2048;
        char* ldsB1 = (char*)(lds + 6144) + w * 2048;
#pragma unroll
        for (int n = 0; n < 2; ++n) {
            const int s   = w * 128 + n * 64 + lane;
            const int row = s >> 3;
            const int c   = s & 7;
            const int fo  = 4 * (c ^ (row & 7));        // swizzled float offset
            gAst[n] = (const char*)(src + (size_t)(iBase + row) * DDIM + fo);
            gBst[n] = (const char*)(src + (size_t)(jBase + row) * DDIM + fo);
        }

#define STAGE0(DC) do { const int _o = (DC) * 128;                            \
        GLL16(gAst[0] + _o, ldsA0);        GLL16(gAst[1] + _o, ldsA0 + 1024); \
        GLL16(gBst[0] + _o, ldsB0);        GLL16(gBst[1] + _o, ldsB0 + 1024); \
    } while (0)
#define STAGE1(DC) do { const int _o = (DC) * 128;                            \
        GLL16(gAst[0] + _o, ldsA1);        GLL16(gAst[1] + _o, ldsA1 + 1024); \
        GLL16(gBst[0] + _o, ldsB1);        GLL16(gBst[1] + _o, ldsB1 + 1024); \
    } while (0)

        STAGE0(0);
        __syncthreads();                       // vmcnt(0) drain: chunk 0 ready
#pragma unroll 1
        for (int dc = 0; dc < 32; dc += 2) {
            if (dc + 1 < 32) STAGE1(dc + 1);   // buf1 free since barrier
            COMPUTE(Ab0, Bb0);
            __syncthreads();                   // drains vmcnt -> buf1 ready
            if (dc + 2 < 32) STAGE0(dc + 2);
            COMPUTE(Ab1, Bb1);
            __syncthreads();
        }
    } else {
        // -------- fallback: single-buffer, register prefetch + divide in
        // staging (round-6 proven path).
        float* As = lds;
        float* Bs = lds + 2048;
        const int r0  = t >> 3;
        const int q0  = t & 7;
        const int swz = 4 * (q0 ^ (r0 & 7));
        float* Aw0 = As + r0 * 32 + swz;
        float* Aw1 = As + (r0 + 32) * 32 + swz;
        float* Bw0 = Bs + r0 * 32 + swz;
        float* Bw1 = Bs + (r0 + 32) * 32 + swz;
        const float* gA0 = src + (size_t)(iBase + r0) * DDIM + 4 * q0;
        const float* gA1 = src + (size_t)(iBase + r0 + 32) * DDIM + 4 * q0;
        const float* gB0 = src + (size_t)(jBase + r0) * DDIM + 4 * q0;
        const float* gB1 = src + (size_t)(jBase + r0 + 32) * DDIM + 4 * q0;
        const float rA0 = rowmax[iBase + r0], rA1 = rowmax[iBase + r0 + 32];
        const float rB0 = rowmax[jBase + r0], rB1 = rowmax[jBase + r0 + 32];

        float4 pa0 = *(const float4*)(gA0);
        float4 pa1 = *(const float4*)(gA1);
        float4 pb0 = *(const float4*)(gB0);
        float4 pb1 = *(const float4*)(gB1);

#pragma unroll 1
        for (int dc = 0; dc < DDIM / 32; ++dc) {
            __syncthreads();
            pa0.x /= rA0; pa0.y /= rA0; pa0.z /= rA0; pa0.w /= rA0;
            pa1.x /= rA1; pa1.y /= rA1; pa1.z /= rA1; pa1.w /= rA1;
            pb0.x /= rB0; pb0.y /= rB0; pb0.z /= rB0; pb0.w /= rB0;
            pb1.x /= rB1; pb1.y /= rB1; pb1.z /= rB1; pb1.w /= rB1;
            *(float4*)Aw0 = pa0;
            *(float4*)Aw1 = pa1;
            *(float4*)Bw0 = pb0;
            *(float4*)Bw1 = pb1;
            __syncthreads();
            if (dc + 1 < DDIM / 32) {
                const int dB = (dc + 1) * 32;
                pa0 = *(const float4*)(gA0 + dB);
                pa1 = *(const float4*)(gA1 + dB);
                pb0 = *(const float4*)(gB0 + dB);
                pb1 = *(const float4*)(gB1 + dB);
            }
            COMPUTE(Ab0, Bb0);
        }
    }

    // Labels (only wave 0 needs them) issued early to hide latency under merge.
    int lA[8], lB[8];
    if (w == 0) {
#pragma unroll
        for (int kk = 0; kk < 8; ++kk) lA[kk] = labels[iBase + ty8 + 8 * kk];
#pragma unroll
        for (int jj = 0; jj < 8; ++jj) lB[jj] = labels[jBase + tx8 + 8 * jj];
    }

    // ---- Tree max-merge of the 4 q-partial accumulators into wave 0. ----
    // mbuf layout: lane L, float4-group g at float index L*64 + 4*(g^(L&15)).
    float* mbuf = lds;                   // first 16 KB; staging buffers dead
    __syncthreads();
#define WRITE_ACC() do {                                                     \
    _Pragma("unroll")                                                        \
    for (int g = 0; g < 16; ++g) {                                           \
        float4 v;                                                            \
        v.x = acc[g >> 1][(g & 1) * 4 + 0]; v.y = acc[g >> 1][(g & 1) * 4 + 1]; \
        v.z = acc[g >> 1][(g & 1) * 4 + 2]; v.w = acc[g >> 1][(g & 1) * 4 + 3]; \
        *(float4*)(mbuf + lane * 64 + 4 * (g ^ (lane & 15))) = v;            \
    } } while (0)
#define MERGE_ACC() do {                                                     \
    _Pragma("unroll")                                                        \
    for (int g = 0; g < 16; ++g) {                                           \
        float4 v = *(const float4*)(mbuf + lane * 64 + 4 * (g ^ (lane & 15))); \
        acc[g >> 1][(g & 1) * 4 + 0] = fmaxf(acc[g >> 1][(g & 1) * 4 + 0], v.x); \
        acc[g >> 1][(g & 1) * 4 + 1] = fmaxf(acc[g >> 1][(g & 1) * 4 + 1], v.y); \
        acc[g >> 1][(g & 1) * 4 + 2] = fmaxf(acc[g >> 1][(g & 1) * 4 + 2], v.z); \
        acc[g >> 1][(g & 1) * 4 + 3] = fmaxf(acc[g >> 1][(g & 1) * 4 + 3], v.w); \
    } } while (0)
    if (w == 2) WRITE_ACC();
    __syncthreads();
    if (w == 0) MERGE_ACC();
    __syncthreads();
    if (w == 3) WRITE_ACC();
    __syncthreads();
    if (w == 1) { MERGE_ACC(); WRITE_ACC(); }   // same-lane read->write, no race
    __syncthreads();
    if (w == 0) MERGE_ACC();

    if (w == 0) {
        // ---- Orientation 1: per column (tb-tile), min over this block's rows.
#pragma unroll
        for (int jj = 0; jj < 8; ++jj) {
            float bv = FLT_MAX; int bi = 0x7fffffff;
#pragma unroll
            for (int kk = 0; kk < 8; ++kk) {
                const int i = iBase + ty8 + 8 * kk;
                const float v = (lA[kk] == lB[jj]) ? FLT_MAX : acc[kk][jj];
                MERGE(bv, bi, v, i);
            }
#pragma unroll
            for (int off = 1; off <= 4; off <<= 1) {     // reduce over ty8
                const float ov = __shfl_xor(bv, off);
                const int   oi = __shfl_xor(bi, off);
                MERGE(bv, bi, ov, oi);
            }
            if (ty8 == 0) {
                const int j = jBase + tx8 + 8 * jj;
                pval[ta * NROWS + j] = bv;
                pidx[ta * NROWS + j] = bi;
            }
        }
        // ---- Orientation 2: per row (ta-tile), min over this block's cols.
#pragma unroll
        for (int kk = 0; kk < 8; ++kk) {
            float bv = FLT_MAX; int bi = 0x7fffffff;
#pragma unroll
            for (int jj = 0; jj < 8; ++jj) {
                const int j = jBase + tx8 + 8 * jj;
                const float v = (lA[kk] == lB[jj]) ? FLT_MAX : acc[kk][jj];
                MERGE(bv, bi, v, j);
            }
#pragma unroll
            for (int off = 8; off <= 32; off <<= 1) {    // reduce over tx8
                const float ov = __shfl_xor(bv, off);
                const int   oi = __shfl_xor(bi, off);
                MERGE(bv, bi, ov, oi);
            }
            if (tx8 == 0) {
                const int i = iBase + ty8 + 8 * kk;
                pval[(tb + 1) * NROWS + i] = bv;
                pidx[(tb + 1) * NROWS + i] = bi;
            }
        }
    }
}

// ---------------------------------------------------------------------------
// Kernel 3a: combine 65 partial slots per column; write indices + colmin.
// ---------------------------------------------------------------------------
__global__ __launch_bounds__(256) void finalizeA_kernel(const float* __restrict__ pval,
                                                        const int* __restrict__ pidx,
                                                        const int* __restrict__ image_idxs,
                                                        float* __restrict__ out,
                                                        float* __restrict__ colmin) {
    const int j = blockIdx.x * 256 + threadIdx.x;
    float bv = FLT_MAX; int bi = 0x7fffffff;
    for (int s = 0; s < NSLOT; ++s) {
        const float v = pval[s * NROWS + j];
        const int   i = pidx[s * NROWS + j];
        MERGE(bv, bi, v, i);
    }
    out[1 + j] = (float)image_idxs[bi];
    colmin[j] = bv;
}

// Kernel 3b: deterministic sum of colmin -> loss.
__global__ __launch_bounds__(256) void finalizeB_kernel(const float* __restrict__ colmin,
                                                        float* __restrict__ out) {
    const int t = threadIdx.x;
    float s = 0.0f;
#pragma unroll
    for (int k = 0; k < 16; ++k) s += colmin[t + 256 * k];
#pragma unroll
    for (int off = 32; off > 0; off >>= 1) s += __shfl_xor(s, off);
    __shared__ float ss[4];
    if ((t & 63) == 0) ss[t >> 6] = s;
    __syncthreads();
    if (t == 0) out[0] = (ss[0] + ss[1] + ss[2] + ss[3]) / (float)NROWS;
}

// ---------------------------------------------------------------------------
extern "C" void kernel_launch(void* const* d_in, const int* in_sizes, int n_in,
                              void* d_out, int out_size, void* d_ws, size_t ws_size,
                              hipStream_t stream) {
    const float* feats      = (const float*)d_in[0];
    const int*   labels     = (const int*)d_in[1];
    const int*   image_idxs = (const int*)d_in[2];
    const int*   normflag   = (const int*)d_in[3];
    float*       out        = (float*)d_out;

    const size_t normBytes = (size_t)NROWS * DDIM * sizeof(float);          // 16 MB
    const size_t partBytes = (size_t)NSLOT * NROWS * 8 + NROWS * 4;         // ~2.15 MB

    if (ws_size >= normBytes + partBytes) {
        float* normf  = (float*)d_ws;
        float* pval   = (float*)((char*)d_ws + normBytes);
        int*   pidx   = (int*)(pval + NSLOT * NROWS);
        float* colmin = (float*)(pidx + NSLOT * NROWS);
        normalize_kernel<<<NROWS / 4, 256, 0, stream>>>(feats, normflag, normf);
        cheb_kernel<false><<<NBLK, 256, 0, stream>>>(normf, nullptr, labels, pval, pidx);
        finalizeA_kernel<<<NROWS / 256, 256, 0, stream>>>(pval, pidx, image_idxs, out, colmin);
        finalizeB_kernel<<<1, 256, 0, stream>>>(colmin, out);
    } else {
        float* rowmax = (float*)d_ws;
        float* pval   = rowmax + NROWS;
        int*   pidx   = (int*)(pval + NSLOT * NROWS);
        float* colmin = (float*)(pidx + NSLOT * NROWS);
        rowmax_kernel<<<NROWS / 4, 256, 0, stream>>>(feats, normflag, rowmax);
        cheb_kernel<true><<<NBLK, 256, 0, stream>>>(feats, rowmax, labels, pval, pidx);
        finalizeA_kernel<<<NROWS / 256, 256, 0, stream>>>(pval, pidx, image_idxs, out, colmin);
        finalizeB_kernel<<<1, 256, 0, stream>>>(colmin, out);
    }
}

// Round 8
// 356.504 us; speedup vs baseline: 2.0243x; 2.0243x over previous
//
#include <hip/hip_runtime.h>
#include <hip/hip_bf16.h>
#include <cfloat>

#define NROWS 4096
#define DDIM 1024
#define NT 64                    // 64x64 tiles per dimension
#define NBLK (NT * (NT + 1) / 2) // 2080 triangular blocks
#define NSLOT (NT + 1)           // 65 partial slots per column

typedef float f2 __attribute__((ext_vector_type(2)));

// acc = max(acc, |x|, |y|) -> v_max3_f32 with abs source modifiers.
#define MAX3ABS(ACC, X, Y) (ACC) = fmaxf(fmaxf(fabsf(X), fabsf(Y)), (ACC))

// lexicographic (val, idx) merge: keep smaller val, tie -> smaller idx
#define MERGE(BV, BI, V, I) \
    do { if ((V) < (BV) || ((V) == (BV) && (I) < (BI))) { BV = (V); BI = (I); } } while (0)

// ---------------------------------------------------------------------------
// Kernel 1a: per-row max + normalize into ws (fast path). One wave per row.
// ---------------------------------------------------------------------------
__global__ __launch_bounds__(256) void normalize_kernel(const float* __restrict__ feats,
                                                        const int* __restrict__ normflag,
                                                        float* __restrict__ normf) {
    const int wave = threadIdx.x >> 6;
    const int lane = threadIdx.x & 63;
    const int row  = blockIdx.x * 4 + wave;
    const float* fr = feats + (size_t)row * DDIM;
    float*       fw = normf + (size_t)row * DDIM;
    float4 v[4];
    float m = 0.0f;  // feats uniform [0,1): nonnegative
#pragma unroll
    for (int k = 0; k < 4; ++k) {
        v[k] = *(const float4*)(fr + lane * 4 + k * 256);
        m = fmaxf(fmaxf(fmaxf(m, v[k].x), fmaxf(v[k].y, v[k].z)), v[k].w);
    }
#pragma unroll
    for (int off = 32; off > 0; off >>= 1) m = fmaxf(m, __shfl_xor(m, off));
    const float r = (*normflag != 0) ? m : 1.0f;
#pragma unroll
    for (int k = 0; k < 4; ++k) {
        v[k].x /= r; v[k].y /= r; v[k].z /= r; v[k].w /= r;
        *(float4*)(fw + lane * 4 + k * 256) = v[k];
    }
}

// Kernel 1b (fallback when ws is small): per-row max only.
__global__ __launch_bounds__(256) void rowmax_kernel(const float* __restrict__ feats,
                                                     const int* __restrict__ normflag,
                                                     float* __restrict__ rowmax) {
    const int wave = threadIdx.x >> 6;
    const int lane = threadIdx.x & 63;
    const int row  = blockIdx.x * 4 + wave;
    const float* fr = feats + (size_t)row * DDIM;
    float m = 0.0f;
    for (int d = lane * 4; d < DDIM; d += 256) {
        float4 v = *(const float4*)(fr + d);
        m = fmaxf(fmaxf(fmaxf(m, v.x), fmaxf(v.y, v.z)), v.w);
    }
#pragma unroll
    for (int off = 32; off > 0; off >>= 1) m = fmaxf(m, __shfl_xor(m, off));
    if (lane == 0) rowmax[row] = (*normflag != 0) ? m : 1.0f;
}

// ---------------------------------------------------------------------------
// Kernel 2: 256 threads (4 waves) per triangular 64x64 tile block (round-6
// structure: ds_write staging + register prefetch, NO global_load_lds — that
// path quadrupled HBM fetch and added 1.5 GB of writes in round 7).
// All 4 waves hold full 8x8-per-lane accumulators over the same tile, split
// by q (wave w does q in {2w,2w+1}). Inner body uses float2 ext-vector subs
// (-> v_pk_add_f32, 2 fp32 subs/instr, bit-exact) + v_max3 abs-modifier
// folds: 4 VALU per 4 elems vs 6 before. launch_bounds(256,3): 3 blocks/CU
// (16 KB LDS each) so dephased blocks overlap the LDS pipe with VALU.
// Swizzle q^(row&7): A-reads 8 distinct rows per 16-lane group -> conflict-
// free; B-reads broadcast; staging writes 2-way (free).
// ---------------------------------------------------------------------------
template <bool NORM>
__global__ __launch_bounds__(256, 3) void cheb_kernel(const float* __restrict__ src,
                                                      const float* __restrict__ rowmax,
                                                      const int* __restrict__ labels,
                                                      float* __restrict__ pval,
                                                      int* __restrict__ pidx) {
    // XCD-bijective swizzle (NBLK % 8 == 0), then triangular decode.
    int bid = blockIdx.x;
    bid = (bid & 7) * (NBLK / 8) + (bid >> 3);
    float fs = sqrtf((float)((2 * NT + 1) * (2 * NT + 1) - 8 * bid));
    int ta = (int)(((float)(2 * NT + 1) - fs) * 0.5f);
    while ((ta + 1) * NT - ((ta + 1) * ta) / 2 <= bid) ++ta;      // start(ta+1) <= bid
    while (ta * NT - (ta * (ta - 1)) / 2 > bid) --ta;             // start(ta)  >  bid
    const int tb = ta + (bid - (ta * NT - (ta * (ta - 1)) / 2));
    const int iBase = ta * 64;
    const int jBase = tb * 64;

    const int t    = threadIdx.x;
    const int w    = t >> 6;          // wave 0..3 (q-slice owner)
    const int lane = t & 63;
    const int ty8  = lane & 7;        // row group
    const int tx8  = lane >> 3;       // col group

    __shared__ __align__(16) float lds[4096];   // 16 KB: As | Bs, reused as merge buf
    float* As = lds;
    float* Bs = lds + 2048;

    float acc[8][8];
#pragma unroll
    for (int kk = 0; kk < 8; ++kk)
#pragma unroll
        for (int jj = 0; jj < 8; ++jj) acc[kk][jj] = 0.0f;

    // Staging: thread handles rows r0 and r0+32, chunk q0, for both A and B.
    // (r0+32)&7 == r0&7, so the swizzled offset is shared.
    const int r0  = t >> 3;           // 0..31
    const int q0  = t & 7;
    const int swz = 4 * (q0 ^ (r0 & 7));
    float* Aw0 = As + r0 * 32 + swz;
    float* Aw1 = As + (r0 + 32) * 32 + swz;
    float* Bw0 = Bs + r0 * 32 + swz;
    float* Bw1 = Bs + (r0 + 32) * 32 + swz;
    const float* gA0 = src + (size_t)(iBase + r0) * DDIM + 4 * q0;
    const float* gA1 = src + (size_t)(iBase + r0 + 32) * DDIM + 4 * q0;
    const float* gB0 = src + (size_t)(jBase + r0) * DDIM + 4 * q0;
    const float* gB1 = src + (size_t)(jBase + r0 + 32) * DDIM + 4 * q0;
    float rA0 = 1.0f, rA1 = 1.0f, rB0 = 1.0f, rB1 = 1.0f;
    if (NORM) {
        rA0 = rowmax[iBase + r0]; rA1 = rowmax[iBase + r0 + 32];
        rB0 = rowmax[jBase + r0]; rB1 = rowmax[jBase + r0 + 32];
    }

    const char* Ab = (const char*)As + ty8 * 128;
    const char* Bb = (const char*)Bs + tx8 * 128;

    // Register prefetch of chunk 0.
    float4 pa0 = *(const float4*)(gA0);
    float4 pa1 = *(const float4*)(gA1);
    float4 pb0 = *(const float4*)(gB0);
    float4 pb1 = *(const float4*)(gB1);

#pragma unroll 1
    for (int dc = 0; dc < DDIM / 32; ++dc) {
        __syncthreads();                 // previous chunk's reads complete
        if (NORM) {
            pa0.x /= rA0; pa0.y /= rA0; pa0.z /= rA0; pa0.w /= rA0;
            pa1.x /= rA1; pa1.y /= rA1; pa1.z /= rA1; pa1.w /= rA1;
            pb0.x /= rB0; pb0.y /= rB0; pb0.z /= rB0; pb0.w /= rB0;
            pb1.x /= rB1; pb1.y /= rB1; pb1.z /= rB1; pb1.w /= rB1;
        }
        *(float4*)Aw0 = pa0;
        *(float4*)Aw1 = pa1;
        *(float4*)Bw0 = pb0;
        *(float4*)Bw1 = pb1;
        __syncthreads();

        if (dc + 1 < DDIM / 32) {        // prefetch next chunk; hides under compute
            const int dB = (dc + 1) * 32;
            pa0 = *(const float4*)(gA0 + dB);
            pa1 = *(const float4*)(gA1 + dB);
            pb0 = *(const float4*)(gB0 + dB);
            pb1 = *(const float4*)(gB1 + dB);
        }

#pragma unroll
        for (int qi = 0; qi < 2; ++qi) {
            const int q  = 2 * w + qi;
            const int oa = 16 * (q ^ ty8);
            const int ob = 16 * (q ^ tx8);
            f2 blo[8], bhi[8];
#pragma unroll
            for (int jj = 0; jj < 8; ++jj) {
                const float4 b = *(const float4*)(Bb + jj * 1024 + ob);
                blo[jj] = f2{b.x, b.y};
                bhi[jj] = f2{b.z, b.w};
            }
#pragma unroll
            for (int kk = 0; kk < 8; ++kk) {
                const float4 a = *(const float4*)(Ab + kk * 1024 + oa);
                const f2 alo = f2{a.x, a.y};
                const f2 ahi = f2{a.z, a.w};
#pragma unroll
                for (int jj = 0; jj < 8; ++jj) {
                    const f2 dlo = alo - blo[jj];   // v_pk_add_f32 (neg mod)
                    const f2 dhi = ahi - bhi[jj];
                    MAX3ABS(acc[kk][jj], dlo.x, dlo.y);   // v_max3 abs mods
                    MAX3ABS(acc[kk][jj], dhi.x, dhi.y);
                }
            }
        }
    }

    // Labels (only wave 0 needs them) issued early to hide latency under merge.
    int lA[8], lB[8];
    if (w == 0) {
#pragma unroll
        for (int kk = 0; kk < 8; ++kk) lA[kk] = labels[iBase + ty8 + 8 * kk];
#pragma unroll
        for (int jj = 0; jj < 8; ++jj) lB[jj] = labels[jBase + tx8 + 8 * jj];
    }

    // ---- Tree max-merge of the 4 q-partial accumulators into wave 0. ----
    // mbuf layout: lane L, float4-group g at float index L*64 + 4*(g^(L&15)).
    float* mbuf = lds;                   // As/Bs are dead now
    __syncthreads();
#define WRITE_ACC() do {                                                     \
    _Pragma("unroll")                                                        \
    for (int g = 0; g < 16; ++g) {                                           \
        float4 v;                                                            \
        v.x = acc[g >> 1][(g & 1) * 4 + 0]; v.y = acc[g >> 1][(g & 1) * 4 + 1]; \
        v.z = acc[g >> 1][(g & 1) * 4 + 2]; v.w = acc[g >> 1][(g & 1) * 4 + 3]; \
        *(float4*)(mbuf + lane * 64 + 4 * (g ^ (lane & 15))) = v;            \
    } } while (0)
#define MERGE_ACC() do {                                                     \
    _Pragma("unroll")                                                        \
    for (int g = 0; g < 16; ++g) {                                           \
        float4 v = *(const float4*)(mbuf + lane * 64 + 4 * (g ^ (lane & 15))); \
        acc[g >> 1][(g & 1) * 4 + 0] = fmaxf(acc[g >> 1][(g & 1) * 4 + 0], v.x); \
        acc[g >> 1][(g & 1) * 4 + 1] = fmaxf(acc[g >> 1][(g & 1) * 4 + 1], v.y); \
        acc[g >> 1][(g & 1) * 4 + 2] = fmaxf(acc[g >> 1][(g & 1) * 4 + 2], v.z); \
        acc[g >> 1][(g & 1) * 4 + 3] = fmaxf(acc[g >> 1][(g & 1) * 4 + 3], v.w); \
    } } while (0)
    if (w == 2) WRITE_ACC();
    __syncthreads();
    if (w == 0) MERGE_ACC();
    __syncthreads();
    if (w == 3) WRITE_ACC();
    __syncthreads();
    if (w == 1) { MERGE_ACC(); WRITE_ACC(); }   // same-lane read->write, no race
    __syncthreads();
    if (w == 0) MERGE_ACC();

    if (w == 0) {
        // ---- Orientation 1: per column (tb-tile), min over this block's rows.
#pragma unroll
        for (int jj = 0; jj < 8; ++jj) {
            float bv = FLT_MAX; int bi = 0x7fffffff;
#pragma unroll
            for (int kk = 0; kk < 8; ++kk) {
                const int i = iBase + ty8 + 8 * kk;
                const float v = (lA[kk] == lB[jj]) ? FLT_MAX : acc[kk][jj];
                MERGE(bv, bi, v, i);
            }
#pragma unroll
            for (int off = 1; off <= 4; off <<= 1) {     // reduce over ty8
                const float ov = __shfl_xor(bv, off);
                const int   oi = __shfl_xor(bi, off);
                MERGE(bv, bi, ov, oi);
            }
            if (ty8 == 0) {
                const int j = jBase + tx8 + 8 * jj;
                pval[ta * NROWS + j] = bv;
                pidx[ta * NROWS + j] = bi;
            }
        }
        // ---- Orientation 2: per row (ta-tile), min over this block's cols.
#pragma unroll
        for (int kk = 0; kk < 8; ++kk) {
            float bv = FLT_MAX; int bi = 0x7fffffff;
#pragma unroll
            for (int jj = 0; jj < 8; ++jj) {
                const int j = jBase + tx8 + 8 * jj;
                const float v = (lA[kk] == lB[jj]) ? FLT_MAX : acc[kk][jj];
                MERGE(bv, bi, v, j);
            }
#pragma unroll
            for (int off = 8; off <= 32; off <<= 1) {    // reduce over tx8
                const float ov = __shfl_xor(bv, off);
                const int   oi = __shfl_xor(bi, off);
                MERGE(bv, bi, ov, oi);
            }
            if (tx8 == 0) {
                const int i = iBase + ty8 + 8 * kk;
                pval[(tb + 1) * NROWS + i] = bv;
                pidx[(tb + 1) * NROWS + i] = bi;
            }
        }
    }
}

// ---------------------------------------------------------------------------
// Kernel 3a: combine 65 partial slots per column; write indices + colmin.
// ---------------------------------------------------------------------------
__global__ __launch_bounds__(256) void finalizeA_kernel(const float* __restrict__ pval,
                                                        const int* __restrict__ pidx,
                                                        const int* __restrict__ image_idxs,
                                                        float* __restrict__ out,
                                                        float* __restrict__ colmin) {
    const int j = blockIdx.x * 256 + threadIdx.x;
    float bv = FLT_MAX; int bi = 0x7fffffff;
    for (int s = 0; s < NSLOT; ++s) {
        const float v = pval[s * NROWS + j];
        const int   i = pidx[s * NROWS + j];
        MERGE(bv, bi, v, i);
    }
    out[1 + j] = (float)image_idxs[bi];
    colmin[j] = bv;
}

// Kernel 3b: deterministic sum of colmin -> loss.
__global__ __launch_bounds__(256) void finalizeB_kernel(const float* __restrict__ colmin,
                                                        float* __restrict__ out) {
    const int t = threadIdx.x;
    float s = 0.0f;
#pragma unroll
    for (int k = 0; k < 16; ++k) s += colmin[t + 256 * k];
#pragma unroll
    for (int off = 32; off > 0; off >>= 1) s += __shfl_xor(s, off);
    __shared__ float ss[4];
    if ((t & 63) == 0) ss[t >> 6] = s;
    __syncthreads();
    if (t == 0) out[0] = (ss[0] + ss[1] + ss[2] + ss[3]) / (float)NROWS;
}

// ---------------------------------------------------------------------------
extern "C" void kernel_launch(void* const* d_in, const int* in_sizes, int n_in,
                              void* d_out, int out_size, void* d_ws, size_t ws_size,
                              hipStream_t stream) {
    const float* feats      = (const float*)d_in[0];
    const int*   labels     = (const int*)d_in[1];
    const int*   image_idxs = (const int*)d_in[2];
    const int*   normflag   = (const int*)d_in[3];
    float*       out        = (float*)d_out;

    const size_t normBytes = (size_t)NROWS * DDIM * sizeof(float);          // 16 MB
    const size_t partBytes = (size_t)NSLOT * NROWS * 8 + NROWS * 4;         // ~2.15 MB

    if (ws_size >= normBytes + partBytes) {
        float* normf  = (float*)d_ws;
        float* pval   = (float*)((char*)d_ws + normBytes);
        int*   pidx   = (int*)(pval + NSLOT * NROWS);
        float* colmin = (float*)(pidx + NSLOT * NROWS);
        normalize_kernel<<<NROWS / 4, 256, 0, stream>>>(feats, normflag, normf);
        cheb_kernel<false><<<NBLK, 256, 0, stream>>>(normf, nullptr, labels, pval, pidx);
        finalizeA_kernel<<<NROWS / 256, 256, 0, stream>>>(pval, pidx, image_idxs, out, colmin);
        finalizeB_kernel<<<1, 256, 0, stream>>>(colmin, out);
    } else {
        float* rowmax = (float*)d_ws;
        float* pval   = rowmax + NROWS;
        int*   pidx   = (int*)(pval + NSLOT * NROWS);
        float* colmin = (float*)(pidx + NSLOT * NROWS);
        rowmax_kernel<<<NROWS / 4, 256, 0, stream>>>(feats, normflag, rowmax);
        cheb_kernel<true><<<NBLK, 256, 0, stream>>>(feats, rowmax, labels, pval, pidx);
        finalizeA_kernel<<<NROWS / 256, 256, 0, stream>>>(pval, pidx, image_idxs, out, colmin);
        finalizeB_kernel<<<1, 256, 0, stream>>>(colmin, out);
    }
}